// Round 1
// baseline (527.082 us; speedup 1.0000x reference)
//
#include <hip/hip_runtime.h>
#include <hip/hip_bf16.h>
#include <stdint.h>

namespace {
constexpr int Bb   = 8;
constexpr int Ff   = 64;
constexpr int Ee   = 49152;
constexpr int Vv   = 16384;
constexpr int F2   = 32;
constexpr int TWOE = 2 * Ee;      // 98304
constexpr int MID  = 96;
constexpr int OUTC = 64;
constexpr int DIMC = 192;
}

// ---------- build occurrence buckets: buckets[v*6 + pos] = endpoint index ----------
__global__ void bucket_fill(const int* __restrict__ conn, int* __restrict__ cnt,
                            int* __restrict__ buckets) {
    int i = blockIdx.x * 256 + threadIdx.x;
    if (i >= TWOE) return;
    int v = conn[i];
    int pos = atomicAdd(&cnt[v], 1);
    if (pos < 6) buckets[v * 6 + pos] = i;
}

// ---------- sort the 6 indices per vertex ascending (restores original-order rank) ----------
__global__ void sort6(int* __restrict__ buckets) {
    int v = blockIdx.x * 256 + threadIdx.x;
    if (v >= Vv) return;
    int a[6];
#pragma unroll
    for (int k = 0; k < 6; ++k) a[k] = buckets[v * 6 + k];
#define CSWAP(x, y) { int lo = min(a[x], a[y]); int hi = max(a[x], a[y]); a[x] = lo; a[y] = hi; }
    // 12-comparator sorting network for 6 elements
    CSWAP(1, 2) CSWAP(4, 5) CSWAP(0, 2) CSWAP(3, 5) CSWAP(0, 1) CSWAP(3, 4)
    CSWAP(2, 5) CSWAP(0, 3) CSWAP(1, 4) CSWAP(2, 4) CSWAP(1, 3) CSWAP(2, 3)
#undef CSWAP
#pragma unroll
    for (int k = 0; k < 6; ++k) buckets[v * 6 + k] = a[k];
}

// ---------- transpose features [B,64,E] -> meshT bf16, meshT[b][e*64 + c] = features[b][c][e] ----------
__global__ __launch_bounds__(256) void transpose_feats(const float* __restrict__ feat,
                                                       __hip_bfloat16* __restrict__ meshT) {
    __shared__ float tile[64][65];
    const int b  = blockIdx.y;
    const int e0 = blockIdx.x * 64;
    const int t  = threadIdx.x;
    const float* src = feat + (size_t)b * Ff * Ee;
#pragma unroll
    for (int k = 0; k < 16; ++k) {
        int idx = k * 256 + t;
        int c = idx >> 6;
        int e = idx & 63;
        tile[c][e] = src[(size_t)c * Ee + e0 + e];
    }
    __syncthreads();
    __hip_bfloat16* dst = meshT + (size_t)b * ((size_t)Ee * 64) + (size_t)e0 * 64;
#pragma unroll
    for (int k = 0; k < 16; ++k) {
        int idx = k * 256 + t;
        int e = idx >> 6;
        int c = idx & 63;
        dst[e * 64 + c] = __float2bfloat16(tile[c][e]);
    }
}

// ---------- fused gather + MLP ----------
// block = 256 threads handles 64 vertices for one batch b.
template <bool USE_MESHT>
__global__ __launch_bounds__(256) void fused_decode(
    const float* __restrict__ feat,
    const __hip_bfloat16* __restrict__ meshT,
    const int* __restrict__ perm,
    const float* __restrict__ W1, const float* __restrict__ b1,
    const float* __restrict__ W2, const float* __restrict__ b2,
    float* __restrict__ out) {
    __shared__ __align__(16) __hip_bfloat16 xs[64][200]; // 192 + pad (bank spread)
    __shared__ float ys[64][100];                        // 96 + pad
    const int t  = threadIdx.x;
    const int v0 = blockIdx.x * 64;
    const int b  = blockIdx.y;

    if (USE_MESHT) {
        const size_t base = (size_t)b * ((size_t)TWOE * F2);
#pragma unroll
        for (int k = 0; k < 6; ++k) {
            int idx = k * 256 + t;          // 0..1535 chunks of 8 bf16
            int vl  = idx / 24;
            int r   = idx - vl * 24;
            int slot = r >> 2, f8 = r & 3;
            int i = perm[(v0 + vl) * 6 + slot];
            uint4 d = *reinterpret_cast<const uint4*>(
                reinterpret_cast<const ushort*>(meshT) + base + (size_t)i * 32 + f8 * 8);
            *reinterpret_cast<uint4*>(&xs[vl][slot * 32 + f8 * 8]) = d;
        }
    } else {
#pragma unroll
        for (int k = 0; k < 48; ++k) {
            int idx = k * 256 + t;          // 0..12287 scalars
            int vl  = idx / 192;
            int c   = idx - vl * 192;
            int slot = c >> 5, f = c & 31;
            int i = perm[(v0 + vl) * 6 + slot];
            float val = feat[((size_t)b * Ff + (size_t)((i & 1) * F2 + f)) * Ee + (i >> 1)];
            xs[vl][c] = __float2bfloat16(val);
        }
    }
    __syncthreads();

    // ---- y = relu(x @ W1 + b1): thread t -> vertex v = t>>2, 24 outputs og..og+23 ----
    const int v  = t >> 2;
    const int og = (t & 3) * 24;
    float acc[24];
#pragma unroll
    for (int j = 0; j < 24; ++j) acc[j] = b1[og + j];
    for (int i = 0; i < DIMC; ++i) {
        float xv = __bfloat162float(xs[v][i]);
        const float4* w = reinterpret_cast<const float4*>(W1 + (size_t)i * MID + og);
#pragma unroll
        for (int q = 0; q < 6; ++q) {
            float4 wq = w[q];
            acc[q * 4 + 0] += xv * wq.x;
            acc[q * 4 + 1] += xv * wq.y;
            acc[q * 4 + 2] += xv * wq.z;
            acc[q * 4 + 3] += xv * wq.w;
        }
    }
#pragma unroll
    for (int j = 0; j < 24; ++j) ys[v][og + j] = fmaxf(acc[j], 0.0f);
    __syncthreads();

    // ---- out = relu(y @ W2 + b2): thread t -> vertex v, 16 outputs og2..og2+15 ----
    const int og2 = (t & 3) * 16;
    float acc2[16];
#pragma unroll
    for (int j = 0; j < 16; ++j) acc2[j] = b2[og2 + j];
    for (int m = 0; m < MID; ++m) {
        float yv = ys[v][m];
        const float4* w = reinterpret_cast<const float4*>(W2 + (size_t)m * OUTC + og2);
#pragma unroll
        for (int q = 0; q < 4; ++q) {
            float4 wq = w[q];
            acc2[q * 4 + 0] += yv * wq.x;
            acc2[q * 4 + 1] += yv * wq.y;
            acc2[q * 4 + 2] += yv * wq.z;
            acc2[q * 4 + 3] += yv * wq.w;
        }
    }
    const size_t obase = ((size_t)(b * OUTC + og2) << 14) + (size_t)(v0 + v);
#pragma unroll
    for (int j = 0; j < 16; ++j)
        out[obase + ((size_t)j << 14)] = fmaxf(acc2[j], 0.0f);
}

extern "C" void kernel_launch(void* const* d_in, const int* in_sizes, int n_in,
                              void* d_out, int out_size, void* d_ws, size_t ws_size,
                              hipStream_t stream) {
    const float* feat = (const float*)d_in[0];
    const int*   conn = (const int*)d_in[1];
    const float* W1   = (const float*)d_in[3];
    const float* b1   = (const float*)d_in[4];
    const float* W2   = (const float*)d_in[5];
    const float* b2   = (const float*)d_in[6];
    float* out = (float*)d_out;

    char* ws = (char*)d_ws;
    int* cnt  = (int*)ws;                              // V ints
    int* perm = (int*)(ws + (size_t)Vv * 4);           // 2E ints (buckets, sorted in place)
    __hip_bfloat16* meshT = (__hip_bfloat16*)(ws + (size_t)Vv * 4 + (size_t)TWOE * 4);
    const size_t need = (size_t)Vv * 4 + (size_t)TWOE * 4 + (size_t)Bb * TWOE * F2 * 2;
    const bool use_mesht = (ws_size >= need);

    hipMemsetAsync(cnt, 0, (size_t)Vv * 4, stream);
    bucket_fill<<<(TWOE + 255) / 256, 256, 0, stream>>>(conn, cnt, perm);
    sort6<<<(Vv + 255) / 256, 256, 0, stream>>>(perm);
    if (use_mesht) {
        transpose_feats<<<dim3(Ee / 64, Bb), 256, 0, stream>>>(feat, meshT);
        fused_decode<true><<<dim3(Vv / 64, Bb), 256, 0, stream>>>(
            feat, meshT, perm, W1, b1, W2, b2, out);
    } else {
        fused_decode<false><<<dim3(Vv / 64, Bb), 256, 0, stream>>>(
            feat, nullptr, perm, W1, b1, W2, b2, out);
    }
}

// Round 3
// 72.010 us; speedup vs baseline: 7.3196x; 7.3196x over previous
//
#include <hip/hip_runtime.h>
#include <hip/hip_bf16.h>
#include <stdint.h>

namespace {
constexpr int Bb   = 8;
constexpr int Ff   = 64;
constexpr int Ee   = 49152;
constexpr int Vv   = 16384;
constexpr int F2   = 32;
constexpr int TWOE = 2 * Ee;      // 98304
constexpr int MID  = 96;
constexpr int OUTC = 64;
constexpr int DIMC = 192;
}

typedef __attribute__((ext_vector_type(8))) short bf16x8;
typedef __attribute__((ext_vector_type(4))) float f32x4;

// ---------- zero the per-vertex counters (kernel instead of memset: graph-safe, deterministic) ----------
__global__ void zero_cnt(int* __restrict__ cnt) {
    int i = blockIdx.x * 256 + threadIdx.x;
    if (i < Vv) cnt[i] = 0;
}

// ---------- build occurrence buckets: buckets[v*6 + pos] = endpoint index ----------
__global__ void bucket_fill(const int* __restrict__ conn, int* __restrict__ cnt,
                            int* __restrict__ buckets) {
    int i = blockIdx.x * 256 + threadIdx.x;
    if (i >= TWOE) return;
    int v = conn[i];
    int pos = atomicAdd(&cnt[v], 1);
    if (pos < 6) buckets[v * 6 + pos] = i;
}

// ---------- sort the 6 indices per vertex ascending (restores original-order rank) ----------
__global__ void sort6(int* __restrict__ buckets) {
    int v = blockIdx.x * 256 + threadIdx.x;
    if (v >= Vv) return;
    int a[6];
#pragma unroll
    for (int k = 0; k < 6; ++k) a[k] = buckets[v * 6 + k];
#define CSWAP(x, y) { int lo = min(a[x], a[y]); int hi = max(a[x], a[y]); a[x] = lo; a[y] = hi; }
    CSWAP(1, 2) CSWAP(4, 5) CSWAP(0, 2) CSWAP(3, 5) CSWAP(0, 1) CSWAP(3, 4)
    CSWAP(2, 5) CSWAP(0, 3) CSWAP(1, 4) CSWAP(2, 4) CSWAP(1, 3) CSWAP(2, 3)
#undef CSWAP
#pragma unroll
    for (int k = 0; k < 6; ++k) buckets[v * 6 + k] = a[k];
}

// ---------- transpose features [B,64,E] -> meshT bf16: meshT[b][e*64 + c] = feat[b][c][e] ----------
__global__ __launch_bounds__(256) void transpose_feats(const float* __restrict__ feat,
                                                       __hip_bfloat16* __restrict__ meshT) {
    __shared__ float tile[64][65];
    const int b  = blockIdx.y;
    const int e0 = blockIdx.x * 64;
    const int t  = threadIdx.x;
    const float* src = feat + (size_t)b * Ff * Ee;
#pragma unroll
    for (int k = 0; k < 16; ++k) {
        int idx = k * 256 + t;
        int c = idx >> 6;
        int e = idx & 63;
        tile[c][e] = src[(size_t)c * Ee + e0 + e];
    }
    __syncthreads();
    __hip_bfloat16* dst = meshT + (size_t)b * ((size_t)Ee * 64) + (size_t)e0 * 64;
#pragma unroll
    for (int k = 0; k < 16; ++k) {
        int idx = k * 256 + t;
        int e = idx >> 6;
        int c = idx & 63;
        dst[e * 64 + c] = __float2bfloat16(tile[c][e]);
    }
}

// ---------- pack weights into MFMA B-fragment order (bf16) ----------
// w1f[((kk*6+nt)*64 + l)*8 + j] = W1[kk*32 + (l>>4)*8 + j][nt*16 + (l&15)]
// w2f[((kk*4+nt)*64 + l)*8 + j] = W2[kk*32 + (l>>4)*8 + j][nt*16 + (l&15)]
__global__ void prep_weights(const float* __restrict__ W1, const float* __restrict__ W2,
                             __hip_bfloat16* __restrict__ w1f, __hip_bfloat16* __restrict__ w2f) {
    int tid = blockIdx.x * 256 + threadIdx.x;   // 0 .. 24575
    if (tid < 18432) {
        int j = tid & 7, l = (tid >> 3) & 63, ft = tid >> 9;   // ft = kk*6+nt
        int kk = ft / 6, nt = ft - kk * 6;
        int k = kk * 32 + (l >> 4) * 8 + j;
        int n = nt * 16 + (l & 15);
        w1f[tid] = __float2bfloat16(W1[k * MID + n]);
    } else if (tid < 24576) {
        int t2 = tid - 18432;
        int j = t2 & 7, l = (t2 >> 3) & 63, ft = t2 >> 9;      // ft = kk*4+nt
        int kk = ft >> 2, nt = ft & 3;
        int k = kk * 32 + (l >> 4) * 8 + j;
        int n = nt * 16 + (l & 15);
        w2f[t2] = __float2bfloat16(W2[k * OUTC + n]);
    }
}

// ---------- fused gather + 2x MFMA MLP; 4 waves/block ----------
// All cross-lane LDS communication is barrier-protected (R2 post-mortem: the
// barrier-free "wave-private" variant diverged on graph replays).
__global__ __launch_bounds__(256, 4) void fused_mfma(
    const __hip_bfloat16* __restrict__ meshT,
    const int* __restrict__ perm,
    const __hip_bfloat16* __restrict__ w1f, const float* __restrict__ b1,
    const __hip_bfloat16* __restrict__ w2f, const float* __restrict__ b2,
    float* __restrict__ out)
{
    __shared__ __align__(16) __hip_bfloat16 xs[64][200];  // 192 + 8 pad
    __shared__ __align__(16) __hip_bfloat16 ys[64][104];  // 96 + 8 pad
    const int t   = threadIdx.x;
    const int l   = t & 63;
    const int wid = t >> 6;
    const int b   = blockIdx.y;
    const int v0  = blockIdx.x * 64 + wid * 16;     // this wave's vertex base
    const int lr  = l & 15;                          // lane row/col within 16x16 tile
    const int lg  = l >> 4;                          // lane group 0..3

    // ---- gather 16 verts x 6 slots x 32 bf16 (64B chunks), 6 x 16B per lane ----
    const ushort* mbase = (const ushort*)meshT + (size_t)b * ((size_t)TWOE * F2);
#pragma unroll
    for (int it = 0; it < 6; ++it) {
        int flat = it * 64 + l;          // 0..383  = 16v * 6s * 4chunks
        int vl = flat / 24;
        int r  = flat - vl * 24;
        int s  = r >> 2, c = r & 3;
        int i  = perm[(v0 + vl) * 6 + s];
        uint4 d = *reinterpret_cast<const uint4*>(mbase + (size_t)i * F2 + c * 8);
        *reinterpret_cast<uint4*>(&xs[wid * 16 + vl][s * 32 + c * 8]) = d;
    }
    __syncthreads();   // gather (cross-lane LDS writes) -> MFMA A-fragment reads

    // ---- GEMM1: Y[16x96] = relu(X[16x192] @ W1 + b1), MFMA 16x16x32 ----
    f32x4 acc[6];
#pragma unroll
    for (int nt = 0; nt < 6; ++nt) {
        float bv = b1[nt * 16 + lr];
        acc[nt] = (f32x4){bv, bv, bv, bv};
    }
#pragma unroll
    for (int kk = 0; kk < 6; ++kk) {
        bf16x8 a = *reinterpret_cast<const bf16x8*>(&xs[wid * 16 + lr][kk * 32 + lg * 8]);
#pragma unroll
        for (int nt = 0; nt < 6; ++nt) {
            bf16x8 w = *reinterpret_cast<const bf16x8*>(w1f + ((size_t)((kk * 6 + nt) * 64 + l) * 8));
            acc[nt] = __builtin_amdgcn_mfma_f32_16x16x32_bf16(a, w, acc[nt], 0, 0, 0);
        }
    }
    // relu -> bf16 -> ys (D layout: row=(lg*4+r), col=lr)
#pragma unroll
    for (int nt = 0; nt < 6; ++nt) {
#pragma unroll
        for (int r = 0; r < 4; ++r) {
            ys[wid * 16 + lg * 4 + r][nt * 16 + lr] = __float2bfloat16(fmaxf(acc[nt][r], 0.0f));
        }
    }
    __syncthreads();   // ys writes (cross-lane) -> GEMM2 A-fragment reads

    // ---- GEMM2: O[16x64] = relu(Y[16x96] @ W2 + b2) ----
    f32x4 acc2[4];
#pragma unroll
    for (int nt = 0; nt < 4; ++nt) {
        float bv = b2[nt * 16 + lr];
        acc2[nt] = (f32x4){bv, bv, bv, bv};
    }
#pragma unroll
    for (int kk = 0; kk < 3; ++kk) {
        bf16x8 a = *reinterpret_cast<const bf16x8*>(&ys[wid * 16 + lr][kk * 32 + lg * 8]);
#pragma unroll
        for (int nt = 0; nt < 4; ++nt) {
            bf16x8 w = *reinterpret_cast<const bf16x8*>(w2f + ((size_t)((kk * 4 + nt) * 64 + l) * 8));
            acc2[nt] = __builtin_amdgcn_mfma_f32_16x16x32_bf16(a, w, acc2[nt], 0, 0, 0);
        }
    }

    // ---- write out[b][o][v]: lane covers o = nt*16+lr, v = v0 + lg*4 + r (float4 over r) ----
    const int vbase = v0 + lg * 4;
#pragma unroll
    for (int nt = 0; nt < 4; ++nt) {
        f32x4 o4;
#pragma unroll
        for (int r = 0; r < 4; ++r) o4[r] = fmaxf(acc2[nt][r], 0.0f);
        *reinterpret_cast<f32x4*>(out + (((size_t)(b * OUTC + nt * 16 + lr)) << 14) + vbase) = o4;
    }
}

extern "C" void kernel_launch(void* const* d_in, const int* in_sizes, int n_in,
                              void* d_out, int out_size, void* d_ws, size_t ws_size,
                              hipStream_t stream) {
    const float* feat = (const float*)d_in[0];
    const int*   conn = (const int*)d_in[1];
    const float* W1   = (const float*)d_in[3];
    const float* b1   = (const float*)d_in[4];
    const float* W2   = (const float*)d_in[5];
    const float* b2   = (const float*)d_in[6];
    float* out = (float*)d_out;

    char* ws = (char*)d_ws;
    int* cnt  = (int*)ws;                                        // V ints      (64 KB)
    int* perm = (int*)(ws + (size_t)Vv * 4);                     // 2E ints     (384 KB)
    __hip_bfloat16* meshT = (__hip_bfloat16*)(ws + (size_t)Vv * 4 + (size_t)TWOE * 4);
    size_t meshT_bytes = (size_t)Bb * TWOE * F2 * 2;             // 50.33 MB
    __hip_bfloat16* w1f = (__hip_bfloat16*)((char*)meshT + meshT_bytes);
    __hip_bfloat16* w2f = w1f + 18432;

    zero_cnt<<<(Vv + 255) / 256, 256, 0, stream>>>(cnt);
    bucket_fill<<<(TWOE + 255) / 256, 256, 0, stream>>>(conn, cnt, perm);
    sort6<<<(Vv + 255) / 256, 256, 0, stream>>>(perm);
    prep_weights<<<96, 256, 0, stream>>>(W1, W2, w1f, w2f);
    transpose_feats<<<dim3(Ee / 64, Bb), 256, 0, stream>>>(feat, meshT);
    fused_mfma<<<dim3(Vv / 64, Bb), 256, 0, stream>>>(meshT, perm, w1f, b1, w2f, b2, out);
}

// Round 4
// 67.503 us; speedup vs baseline: 7.8083x; 1.0668x over previous
//
#include <hip/hip_runtime.h>
#include <hip/hip_bf16.h>
#include <stdint.h>

namespace {
constexpr int Bb   = 8;
constexpr int Ff   = 64;
constexpr int Ee   = 49152;
constexpr int Vv   = 16384;
constexpr int F2   = 32;
constexpr int TWOE = 2 * Ee;      // 98304
constexpr int MID  = 96;
constexpr int OUTC = 64;
}

typedef __attribute__((ext_vector_type(8))) short bf16x8;
typedef __attribute__((ext_vector_type(4))) float f32x4;

// ---------- zero the per-vertex counters ----------
__global__ void zero_cnt(int* __restrict__ cnt) {
    int i = blockIdx.x * 256 + threadIdx.x;
    if (i < Vv) cnt[i] = 0;
}

// ---------- build occurrence buckets: buckets[v*6 + pos] = endpoint index ----------
__global__ void bucket_fill(const int* __restrict__ conn, int* __restrict__ cnt,
                            int* __restrict__ buckets) {
    int i = blockIdx.x * 256 + threadIdx.x;
    if (i >= TWOE) return;
    int v = conn[i];
    int pos = atomicAdd(&cnt[v], 1);
    if (pos < 6) buckets[v * 6 + pos] = i;
}

// ---------- sort the 6 indices per vertex, emit inverse perm dest[i] = v*6 + slot ----------
__global__ void sort6_inv(const int* __restrict__ buckets, int* __restrict__ dest) {
    int v = blockIdx.x * 256 + threadIdx.x;
    if (v >= Vv) return;
    int a[6];
#pragma unroll
    for (int k = 0; k < 6; ++k) a[k] = buckets[v * 6 + k];
#define CSWAP(x, y) { int lo = min(a[x], a[y]); int hi = max(a[x], a[y]); a[x] = lo; a[y] = hi; }
    CSWAP(1, 2) CSWAP(4, 5) CSWAP(0, 2) CSWAP(3, 5) CSWAP(0, 1) CSWAP(3, 4)
    CSWAP(2, 5) CSWAP(0, 3) CSWAP(1, 4) CSWAP(2, 4) CSWAP(1, 3) CSWAP(2, 3)
#undef CSWAP
#pragma unroll
    for (int k = 0; k < 6; ++k) dest[a[k]] = v * 6 + k;
}

// ---------- pack weights into MFMA B-fragment order (bf16) ----------
__global__ void prep_weights(const float* __restrict__ W1, const float* __restrict__ W2,
                             __hip_bfloat16* __restrict__ w1f, __hip_bfloat16* __restrict__ w2f) {
    int tid = blockIdx.x * 256 + threadIdx.x;   // 0 .. 24575
    if (tid < 18432) {
        int j = tid & 7, l = (tid >> 3) & 63, ft = tid >> 9;   // ft = kk*6+nt
        int kk = ft / 6, nt = ft - kk * 6;
        int k = kk * 32 + (l >> 4) * 8 + j;
        int n = nt * 16 + (l & 15);
        w1f[tid] = __float2bfloat16(W1[k * MID + n]);
    } else if (tid < 24576) {
        int t2 = tid - 18432;
        int j = t2 & 7, l = (t2 >> 3) & 63, ft = t2 >> 9;      // ft = kk*4+nt
        int kk = ft >> 2, nt = ft & 3;
        int k = kk * 32 + (l >> 4) * 8 + j;
        int n = nt * 16 + (l & 15);
        w2f[t2] = __float2bfloat16(W2[k * OUTC + n]);
    }
}

// ---------- transpose + permute in one pass ----------
// Reads feat[b][c][e0:e0+64] coalesced; writes each endpoint's 32-bf16 half-feature
// (64B chunk) directly to its final slot xg[b][dest[i]] (random 64B writes).
__global__ __launch_bounds__(256) void scatter_feats(const float* __restrict__ feat,
                                                     const int* __restrict__ dest,
                                                     ushort* __restrict__ xg) {
    __shared__ float tile[64][65];
    const int b  = blockIdx.y;
    const int e0 = blockIdx.x * 64;
    const int t  = threadIdx.x;
    const float* src = feat + (size_t)b * Ff * Ee;
#pragma unroll
    for (int k = 0; k < 16; ++k) {
        int idx = k * 256 + t;
        int c = idx >> 6;
        int e = idx & 63;
        tile[c][e] = src[(size_t)c * Ee + e0 + e];
    }
    __syncthreads();
    ushort* dst_base = xg + (size_t)b * ((size_t)Vv * 192);
#pragma unroll
    for (int it = 0; it < 2; ++it) {
        int item = it * 256 + t;        // 0..511 = 128 chunks x 4 sub-chunks
        int le = item >> 2, s2 = item & 3;
        int e = le >> 1, h = le & 1;
        int i = e0 * 2 + e * 2 + h;     // endpoint index
        int d = dest[i];                // v*6 + slot
        int c0 = h * 32 + s2 * 8;
        union { ushort u[8]; uint4 q; } pk;
#pragma unroll
        for (int k = 0; k < 8; ++k) {
            __hip_bfloat16 hv = __float2bfloat16(tile[c0 + k][e]);
            pk.u[k] = *reinterpret_cast<ushort*>(&hv);
        }
        *reinterpret_cast<uint4*>(dst_base + (size_t)d * 32 + s2 * 8) = pk.q;
    }
}

// ---------- decode: linear reads of xg, 2x MFMA MLP ----------
__global__ __launch_bounds__(256) void decode_mfma(
    const ushort* __restrict__ xg,
    const __hip_bfloat16* __restrict__ w1f, const float* __restrict__ b1,
    const __hip_bfloat16* __restrict__ w2f, const float* __restrict__ b2,
    float* __restrict__ out)
{
    __shared__ __align__(16) __hip_bfloat16 ys[64][104];  // 96 + 8 pad
    const int t   = threadIdx.x;
    const int l   = t & 63;
    const int wid = t >> 6;
    const int b   = blockIdx.y;
    const int v0  = blockIdx.x * 64 + wid * 16;
    const int lr  = l & 15;
    const int lg  = l >> 4;

    const ushort* xv = xg + ((size_t)b * Vv + v0) * 192;

    // ---- GEMM1: Y[16x96] = relu(X[16x192] @ W1 + b1) ----
    f32x4 acc[6];
#pragma unroll
    for (int nt = 0; nt < 6; ++nt) {
        float bv = b1[nt * 16 + lr];
        acc[nt] = (f32x4){bv, bv, bv, bv};
    }
#pragma unroll
    for (int kk = 0; kk < 6; ++kk) {
        bf16x8 a = *reinterpret_cast<const bf16x8*>(xv + (size_t)lr * 192 + kk * 32 + lg * 8);
#pragma unroll
        for (int nt = 0; nt < 6; ++nt) {
            bf16x8 w = *reinterpret_cast<const bf16x8*>(w1f + ((size_t)((kk * 6 + nt) * 64 + l) * 8));
            acc[nt] = __builtin_amdgcn_mfma_f32_16x16x32_bf16(a, w, acc[nt], 0, 0, 0);
        }
    }
    // relu -> bf16 -> ys (D layout: row=(lg*4+r), col=lr)
#pragma unroll
    for (int nt = 0; nt < 6; ++nt) {
#pragma unroll
        for (int r = 0; r < 4; ++r) {
            ys[wid * 16 + lg * 4 + r][nt * 16 + lr] = __float2bfloat16(fmaxf(acc[nt][r], 0.0f));
        }
    }
    __syncthreads();   // ys cross-lane LDS writes -> GEMM2 A-fragment reads

    // ---- GEMM2: O[16x64] = relu(Y[16x96] @ W2 + b2) ----
    f32x4 acc2[4];
#pragma unroll
    for (int nt = 0; nt < 4; ++nt) {
        float bv = b2[nt * 16 + lr];
        acc2[nt] = (f32x4){bv, bv, bv, bv};
    }
#pragma unroll
    for (int kk = 0; kk < 3; ++kk) {
        bf16x8 a = *reinterpret_cast<const bf16x8*>(&ys[wid * 16 + lr][kk * 32 + lg * 8]);
#pragma unroll
        for (int nt = 0; nt < 4; ++nt) {
            bf16x8 w = *reinterpret_cast<const bf16x8*>(w2f + ((size_t)((kk * 4 + nt) * 64 + l) * 8));
            acc2[nt] = __builtin_amdgcn_mfma_f32_16x16x32_bf16(a, w, acc2[nt], 0, 0, 0);
        }
    }

    // ---- write out[b][o][v]: o = nt*16+lr, v = v0 + lg*4 + r ----
    const int vbase = v0 + lg * 4;
#pragma unroll
    for (int nt = 0; nt < 4; ++nt) {
        f32x4 o4;
#pragma unroll
        for (int r = 0; r < 4; ++r) o4[r] = fmaxf(acc2[nt][r], 0.0f);
        *reinterpret_cast<f32x4*>(out + (((size_t)(b * OUTC + nt * 16 + lr)) << 14) + vbase) = o4;
    }
}

extern "C" void kernel_launch(void* const* d_in, const int* in_sizes, int n_in,
                              void* d_out, int out_size, void* d_ws, size_t ws_size,
                              hipStream_t stream) {
    const float* feat = (const float*)d_in[0];
    const int*   conn = (const int*)d_in[1];
    const float* W1   = (const float*)d_in[3];
    const float* b1   = (const float*)d_in[4];
    const float* W2   = (const float*)d_in[5];
    const float* b2   = (const float*)d_in[6];
    float* out = (float*)d_out;

    char* ws = (char*)d_ws;
    int* cnt     = (int*)ws;                                  // 64 KB
    int* buckets = (int*)(ws + 65536);                        // 384 KB
    int* dest    = (int*)(ws + 65536 + 393216);               // 384 KB
    __hip_bfloat16* w1f = (__hip_bfloat16*)(ws + 65536 + 2 * 393216);   // 36 KB
    __hip_bfloat16* w2f = w1f + 18432;                                  // 12 KB
    ushort* xg = (ushort*)(ws + 65536 + 2 * 393216 + 49152);  // 50.33 MB

    zero_cnt<<<(Vv + 255) / 256, 256, 0, stream>>>(cnt);
    bucket_fill<<<(TWOE + 255) / 256, 256, 0, stream>>>(conn, cnt, buckets);
    sort6_inv<<<(Vv + 255) / 256, 256, 0, stream>>>(buckets, dest);
    prep_weights<<<96, 256, 0, stream>>>(W1, W2, w1f, w2f);
    scatter_feats<<<dim3(Ee / 64, Bb), 256, 0, stream>>>(feat, dest, xg);
    decode_mfma<<<dim3(Vv / 64, Bb), 256, 0, stream>>>(xg, w1f, b1, w2f, b2, out);
}